// Round 9
// baseline (61.949 us; speedup 1.0000x reference)
//
#include <hip/hip_runtime.h>

#define LL    4096
#define OUTL  8191
#define FPAD  272
#define NPDW  2336          // dwords per fwd copy: elements -272..4399
#define CB1   2352          // copy1 base (16-dw gap -> copies on complementary bank halves)
#define RB    4704          // rev-copy base dword
#define BTOP  5887          // rev top x-index (== 7 mod 8)
#define LDSDW 9824          // contains benign prefetch overrun

typedef short v8s __attribute__((ext_vector_type(8)));
typedef float v4f __attribute__((ext_vector_type(4)));

__device__ __forceinline__ unsigned bf16b(float f) {
    unsigned u = __builtin_bit_cast(unsigned, f);
    u += 0x7fff + ((u >> 16) & 1);          // RNE
    return u >> 16;
}
__device__ __forceinline__ unsigned pk(float lo, float hi) {
    return bf16b(lo) | (bf16b(hi) << 16);
}
// B-unit swizzle: bank-quad = (g mod 16)>>1. For a b128 phase (8 lanes,
// unit stride -2, fixed parity) quads are 8 consecutive integers mod 8 ->
// conflict-free. Bijection per 16-block; linear under all loop strides
// (all multiples of 16 units).
__device__ __forceinline__ int swz(int g) {
    return (g & ~15) | ((g & 1) << 3) | ((g & 15) >> 1);
}

struct Frag {
    unsigned x0, x1, x2, x3, y0, y1, y2, y3;   // A tiles u=0,1 (4 dw each)
    uint4 b3, b2, b1, b0;                      // B tiles v=3..0 (load order)
};

__global__ __launch_bounds__(512, 4)
void selfconv_mfma7(const float* __restrict__ xg, float* __restrict__ outg) {
    __shared__ unsigned lds[LDSDW];
    const int tid = threadIdx.x;
    const int blk = blockIdx.x;
    const int b   = blk & 127;
    const int id  = blk >> 7;                       // light regions first
    const int rg  = (id == 0) ? 0 : (id == 1) ? 3 : (id == 2) ? 1 : 2;
    const int T0  = rg << 11;
    const float* __restrict__ xb = xg + b * LL;

    // ---- fwd staging: thread w covers elements E..E+8, E = 8w-272 ----
#pragma unroll
    for (int rr = 0; rr < 2; ++rr) {
        int w = tid + rr * 512;
        if (w < 584) {
            int E = 8 * w - FPAD;
            float e0,e1,e2,e3,e4,e5,e6,e7,e8;
            if (E >= 0 && E + 8 < LL) {             // fast: vector loads
                float4 fa = *(const float4*)(xb + E);
                float4 fb = *(const float4*)(xb + E + 4);
                e0=fa.x; e1=fa.y; e2=fa.z; e3=fa.w;
                e4=fb.x; e5=fb.y; e6=fb.z; e7=fb.w; e8=xb[E+8];
            } else {                                 // edges: guarded scalars
                float t[9];
#pragma unroll
                for (int k = 0; k < 9; ++k) {
                    int e = E + k;
                    t[k] = (e >= 0 && e < LL) ? xb[e] : 0.f;
                }
                e0=t[0]; e1=t[1]; e2=t[2]; e3=t[3]; e4=t[4];
                e5=t[5]; e6=t[6]; e7=t[7]; e8=t[8];
            }
            uint4 d0{pk(e0,e1), pk(e2,e3), pk(e4,e5), pk(e6,e7)};
            uint4 d1{pk(e1,e2), pk(e3,e4), pk(e5,e6), pk(e7,e8)};
            *(uint4*)&lds[4 * w]       = d0;
            *(uint4*)&lds[CB1 + 4 * w] = d1;
        }
    }
    // ---- rev staging: unit g holds yr[8g..8g+7] = x[BTOP-8g-7..BTOP-8g] ----
    {
        int g = 224 + tid;                          // in-range units, aligned
        int x0 = BTOP - 7 - 8 * g;                  // 0..4088, float4-aligned
        float4 fa = *(const float4*)(xb + x0);
        float4 fb = *(const float4*)(xb + x0 + 4);
        uint4 o{pk(fb.w, fb.z), pk(fb.y, fb.x), pk(fa.w, fa.z), pk(fa.y, fa.x)};
        *(uint4*)&lds[RB + 4 * swz(g)] = o;
    }
    // ---- zero rev pads: units [0,224) and [736,992) (16-block closed) ----
    if (tid < 480) {
        int u = (tid < 224) ? tid : tid + 512;
        *(uint4*)&lds[RB + 4 * u] = uint4{0, 0, 0, 0};
    }
    __syncthreads();

    const int wv = tid >> 6, lane = tid & 63, ln16 = lane & 15, q = lane >> 4;

    // i-union over the 8 tiles (A +256u, B +512v)
    int mn = 0x7fffffff, mx = -0x7fffffff;
#pragma unroll
    for (int u = 0; u < 2; ++u)
#pragma unroll
        for (int v = 0; v < 4; ++v) {
            int base = T0 + 256 * u + 512 * v;
            int iLo = base - (LL - 1); if (iLo < 0) iLo = 0;
            int iHi = base + 255;      if (iHi > LL - 1) iHi = LL - 1;
            int a = iLo - 256 * u; if (a < mn) mn = a;
            int c2 = iHi - 256 * u; if (c2 > mx) mx = c2;
        }
    const int base_   = mn - 15;
    const int i0start = base_ - ((base_ - 1) & 7);   // == 1 mod 8
    const int nch     = ((mx - i0start) >> 5) + 1;
    const int nw      = (nch - wv + 7) >> 3;         // 8-way interleaved split
    const int i0w     = i0start + 32 * wv;

    // A: x[i0 + m + 8q + j], m=ln16 — parity selects fwd copy
    const int s0p = i0w + ln16 + 8 * q + FPAD;
    const int aw  = (s0p >> 1) + ((s0p & 1) ? CB1 : 0);
    // B: yr unit base at v=3; subsequent strides all preserve the swizzle key
    const int g3 = (4352 - T0 + i0w - 16 * ln16 + 8 * q) >> 3;   // 4352=BTOP-1535
    const int bw = RB + 4 * swz(g3);

    v4f a00{0,0,0,0}, a01{0,0,0,0}, a02{0,0,0,0}, a03{0,0,0,0};
    v4f a10{0,0,0,0}, a11{0,0,0,0}, a12{0,0,0,0}, a13{0,0,0,0};

    auto ld = [&](Frag& F, int a, int w) {
        F.x0 = lds[a];       F.x1 = lds[a + 1];
        F.x2 = lds[a + 2];   F.x3 = lds[a + 3];
        F.y0 = lds[a + 128]; F.y1 = lds[a + 129];   // A tile u=1 (+256 elems)
        F.y2 = lds[a + 130]; F.y3 = lds[a + 131];
        F.b3 = *(const uint4*)&lds[w];
        F.b2 = *(const uint4*)&lds[w + 256];
        F.b1 = *(const uint4*)&lds[w + 512];
        F.b0 = *(const uint4*)&lds[w + 768];
    };
    auto mkA = [](unsigned u0, unsigned u1, unsigned u2, unsigned u3) {
        union { unsigned x[4]; v8s s; } z;
        z.x[0] = u0; z.x[1] = u1; z.x[2] = u2; z.x[3] = u3; return z.s;
    };
    auto mkB = [](uint4 v) {
        union { unsigned x[4]; v8s s; } z;
        z.x[0] = v.x; z.x[1] = v.y; z.x[2] = v.z; z.x[3] = v.w; return z.s;
    };
    auto cmp = [&](const Frag& F) {      // consume in load-age order: B3 first
        v8s A0 = mkA(F.x0, F.x1, F.x2, F.x3);
        v8s A1 = mkA(F.y0, F.y1, F.y2, F.y3);
        v8s B3 = mkB(F.b3), B2 = mkB(F.b2), B1 = mkB(F.b1), B0 = mkB(F.b0);
        a03 = __builtin_amdgcn_mfma_f32_16x16x32_bf16(A0, B3, a03, 0, 0, 0);
        a13 = __builtin_amdgcn_mfma_f32_16x16x32_bf16(A1, B3, a13, 0, 0, 0);
        a02 = __builtin_amdgcn_mfma_f32_16x16x32_bf16(A0, B2, a02, 0, 0, 0);
        a12 = __builtin_amdgcn_mfma_f32_16x16x32_bf16(A1, B2, a12, 0, 0, 0);
        a01 = __builtin_amdgcn_mfma_f32_16x16x32_bf16(A0, B1, a01, 0, 0, 0);
        a11 = __builtin_amdgcn_mfma_f32_16x16x32_bf16(A1, B1, a11, 0, 0, 0);
        a00 = __builtin_amdgcn_mfma_f32_16x16x32_bf16(A0, B0, a00, 0, 0, 0);
        a10 = __builtin_amdgcn_mfma_f32_16x16x32_bf16(A1, B0, a10, 0, 0, 0);
    };

    // wave-chunk stride: 256 elements = 128 A-dwords = 64 B-units
    Frag F0, F1;
    int awE = aw, bwE = bw, awO = aw + 128, bwO = bw + 128;
    ld(F0, awE, bwE); awE += 256; bwE += 256;
    ld(F1, awO, bwO); awO += 256; bwO += 256;
    int c = 0;
    for (; c + 2 < nw; c += 2) {
        cmp(F0); ld(F0, awE, bwE); awE += 256; bwE += 256;
        cmp(F1); ld(F1, awO, bwO); awO += 256; bwO += 256;
    }
    cmp(F0);
    if (c + 1 < nw) cmp(F1);

    // ---- 8-way reduction (3 stages), stride-36 scratch ----
    float* fs = (float*)lds;
    __syncthreads();
    if (wv >= 4) {
        int sb = (wv - 4) * 2304 + lane * 36;
        *(v4f*)&fs[sb]      = a00; *(v4f*)&fs[sb + 4]  = a10;
        *(v4f*)&fs[sb + 8]  = a01; *(v4f*)&fs[sb + 12] = a11;
        *(v4f*)&fs[sb + 16] = a02; *(v4f*)&fs[sb + 20] = a12;
        *(v4f*)&fs[sb + 24] = a03; *(v4f*)&fs[sb + 28] = a13;
    }
    __syncthreads();
    if (wv < 4) {
        int sb = wv * 2304 + lane * 36;
        a00 += *(const v4f*)&fs[sb];      a10 += *(const v4f*)&fs[sb + 4];
        a01 += *(const v4f*)&fs[sb + 8];  a11 += *(const v4f*)&fs[sb + 12];
        a02 += *(const v4f*)&fs[sb + 16]; a12 += *(const v4f*)&fs[sb + 20];
        a03 += *(const v4f*)&fs[sb + 24]; a13 += *(const v4f*)&fs[sb + 28];
    }
    __syncthreads();
    if (wv >= 1 && wv < 4) {
        int sb = (wv - 1) * 2304 + lane * 36;
        *(v4f*)&fs[sb]      = a00; *(v4f*)&fs[sb + 4]  = a10;
        *(v4f*)&fs[sb + 8]  = a01; *(v4f*)&fs[sb + 12] = a11;
        *(v4f*)&fs[sb + 16] = a02; *(v4f*)&fs[sb + 20] = a12;
        *(v4f*)&fs[sb + 24] = a03; *(v4f*)&fs[sb + 28] = a13;
    }
    __syncthreads();
    if (wv == 0) {
#pragma unroll
        for (int s = 0; s < 3; ++s) {
            int sb = s * 2304 + lane * 36;
            a00 += *(const v4f*)&fs[sb];      a10 += *(const v4f*)&fs[sb + 4];
            a01 += *(const v4f*)&fs[sb + 8];  a11 += *(const v4f*)&fs[sb + 12];
            a02 += *(const v4f*)&fs[sb + 16]; a12 += *(const v4f*)&fs[sb + 20];
            a03 += *(const v4f*)&fs[sb + 24]; a13 += *(const v4f*)&fs[sb + 28];
        }
        float* __restrict__ ob = outg + b * OUTL;
        const v4f* accs[8] = {&a00, &a10, &a01, &a11, &a02, &a12, &a03, &a13};
#pragma unroll
        for (int uv = 0; uv < 8; ++uv) {
            int u = uv & 1, v = uv >> 1;
            int tilebase = T0 + 256 * u + 512 * v;
            int tb = tilebase + 4 * q + 16 * ln16;
            v4f a = *accs[uv];
            if (tilebase + 255 < OUTL) {
                *(v4f*)&ob[tb] = a;                  // coalesced b128 store
            } else {
#pragma unroll
                for (int r2 = 0; r2 < 4; ++r2)
                    if (tb + r2 < OUTL) ob[tb + r2] = a[r2];
            }
        }
    }
}

extern "C" void kernel_launch(void* const* d_in, const int* in_sizes, int n_in,
                              void* d_out, int out_size, void* d_ws, size_t ws_size,
                              hipStream_t stream) {
    const float* x = (const float*)d_in[0];
    float* out = (float*)d_out;
    selfconv_mfma7<<<dim3(512), dim3(512), 0, stream>>>(x, out);
}